// Round 8
// baseline (211.852 us; speedup 1.0000x reference)
//
#include <hip/hip_runtime.h>

typedef unsigned short u16;
typedef unsigned int u32;
typedef __attribute__((ext_vector_type(8))) short bf16x8;
typedef __attribute__((ext_vector_type(4))) float f32x4;
typedef __attribute__((ext_vector_type(16))) float f32x16;

#define TOK   4096   // B*T
#define EMB   1024
#define NQKV  3072
#define TSEQ  2048
#define NH    16

__device__ __forceinline__ u16 f2b(float f) {
  union { float f; unsigned u; } v; v.f = f;
  unsigned r = v.u + 0x7FFFu + ((v.u >> 16) & 1u);
  return (u16)(r >> 16);
}

// pack bf16(a) low16, bf16(b) high16 (round half-up)
__device__ __forceinline__ u32 pack_rn(float a, float b) {
  u32 ua = __float_as_uint(a) + 0x8000u;
  u32 ub = __float_as_uint(b) + 0x8000u;
  return __builtin_amdgcn_perm(ub, ua, 0x07060302u);
}

__device__ __forceinline__ f32x16 zero16() {
  f32x16 z;
#pragma unroll
  for (int i = 0; i < 16; i++) z[i] = 0.f;
  return z;
}

// ---------------- fused prep: x->bf16, w_qkv^T, w_out^T ----------------

__global__ __launch_bounds__(256) void prep_kernel(const float* __restrict__ x,
                                                   u16* __restrict__ x_bf,
                                                   const float* __restrict__ w_qkv,
                                                   u16* __restrict__ wqkvT,
                                                   const float* __restrict__ w_out,
                                                   u16* __restrict__ woutT) {
  __shared__ u16 sm[64][65];
  int bid = blockIdx.x, tid = threadIdx.x;
  if (bid < 4096) {                       // cvt: 1M float4 elements
    int i = bid * 256 + tid;
    float4 v = ((const float4*)x)[i];
    union { u16 us[4]; uint2 u2; } o;
    o.us[0] = f2b(v.x); o.us[1] = f2b(v.y); o.us[2] = f2b(v.z); o.us[3] = f2b(v.w);
    ((uint2*)x_bf)[i] = o.u2;
    return;
  }
  const float* src; u16* dst; int R, C, bx, by;
  if (bid < 4096 + 768) {                 // w_qkv: [1024][3072] -> [3072][1024]
    int t = bid - 4096; bx = t % 48; by = t / 48;
    src = w_qkv; dst = wqkvT; R = EMB; C = NQKV;
  } else {                                // w_out: [1024][1024] -> [1024][1024]
    int t = bid - 4096 - 768; bx = t & 15; by = t >> 4;
    src = w_out; dst = woutT; R = EMB; C = EMB;
  }
  int c0 = bx * 64, r0 = by * 64;
#pragma unroll
  for (int i = 0; i < 16; i++) {
    int idx = tid + i * 256;
    int r = idx >> 6, c = idx & 63;
    sm[r][c] = f2b(src[(size_t)(r0 + r) * C + c0 + c]);
  }
  __syncthreads();
#pragma unroll
  for (int i = 0; i < 16; i++) {
    int idx = tid + i * 256;
    int cc = idx >> 6, rr = idx & 63;
    dst[(size_t)(c0 + cc) * R + r0 + rr] = sm[rr][cc];
  }
}

// per-head transpose: V[bh][t][d] -> Vt[bh][d][t]
__global__ __launch_bounds__(256) void transpose_v(const u16* __restrict__ V,
                                                   u16* __restrict__ Vt) {
  __shared__ u16 sm[64][72];
  int t0 = blockIdx.x * 64, bh = blockIdx.y;
  size_t base = (size_t)bh * TSEQ * 64;
  int tid = threadIdx.x;
  int r = tid >> 2, c = (tid & 3) * 16;
  *(bf16x8*)&sm[r][c]     = *(const bf16x8*)&V[base + (size_t)(t0 + r) * 64 + c];
  *(bf16x8*)&sm[r][c + 8] = *(const bf16x8*)&V[base + (size_t)(t0 + r) * 64 + c + 8];
  __syncthreads();
  int d = tid >> 2, tc = (tid & 3) * 16;
  union { u16 us[16]; uint4 v4[2]; } o;
#pragma unroll
  for (int i = 0; i < 16; i++) o.us[i] = sm[tc + i][d];
  *(uint4*)&Vt[base + (size_t)d * TSEQ + t0 + tc]     = o.v4[0];
  *(uint4*)&Vt[base + (size_t)d * TSEQ + t0 + tc + 8] = o.v4[1];
}

// ---------------- GEMM: C[m][n] = sum_k A[m][k]*Bt[n][k] + bias[n] ----------------
// Stride-68 LDS (<=2-way bank aliasing, free) + register-staged tiles with
// cross-iteration prefetch. C^T orientation -> vectorized epilogue.
// MODE 0: uint2 bf16 scatter into Q/K/V [bh][t][d].  MODE 1: float4 fp32 [M][N].

template <int MODE, int TM>
__global__ __launch_bounds__(256) void gemm_bt(const u16* __restrict__ A,
                                               const u16* __restrict__ Bt,
                                               const float* __restrict__ bias,
                                               u16* __restrict__ qb, u16* __restrict__ kb,
                                               u16* __restrict__ vb, float* __restrict__ outp,
                                               int K, int N) {
  constexpr int LDA = 68;
  constexpr int CT = (TM == 128) ? 4 : 2;
  constexpr int AC = TM / 32;
  __shared__ u16 As[TM][LDA];
  __shared__ u16 Bs[128][LDA];
  int tid = threadIdx.x;
  int m0 = blockIdx.y * TM, n0 = blockIdx.x * 128;
  int lane = tid & 63, wid = tid >> 6;
  int wm = (TM == 128) ? (wid >> 1) * 64 : 0;
  int wn = (TM == 128) ? (wid & 1) * 64 : wid * 32;
  int l15 = lane & 15, quad = lane >> 4;
  int lrow = lane >> 3, lcol = (lane & 7) * 8;

  f32x4 acc[4][CT];
#pragma unroll
  for (int i = 0; i < 4; i++)
#pragma unroll
    for (int j = 0; j < CT; j++) acc[i][j] = (f32x4){0.f, 0.f, 0.f, 0.f};

  bf16x8 ar[AC], br[4];
#pragma unroll
  for (int i = 0; i < AC; i++)
    ar[i] = *(const bf16x8*)&A[(size_t)(m0 + (wid * AC + i) * 8 + lrow) * K + lcol];
#pragma unroll
  for (int i = 0; i < 4; i++)
    br[i] = *(const bf16x8*)&Bt[(size_t)(n0 + (wid * 4 + i) * 8 + lrow) * K + lcol];

  for (int k0 = 0; k0 < K; k0 += 64) {
#pragma unroll
    for (int i = 0; i < AC; i++)
      *(bf16x8*)&As[(wid * AC + i) * 8 + lrow][lcol] = ar[i];
#pragma unroll
    for (int i = 0; i < 4; i++)
      *(bf16x8*)&Bs[(wid * 4 + i) * 8 + lrow][lcol] = br[i];
    __syncthreads();

    if (k0 + 64 < K) {
      int kn = k0 + 64;
#pragma unroll
      for (int i = 0; i < AC; i++)
        ar[i] = *(const bf16x8*)&A[(size_t)(m0 + (wid * AC + i) * 8 + lrow) * K + kn + lcol];
#pragma unroll
      for (int i = 0; i < 4; i++)
        br[i] = *(const bf16x8*)&Bt[(size_t)(n0 + (wid * 4 + i) * 8 + lrow) * K + kn + lcol];
    }

#pragma unroll
    for (int ks = 0; ks < 2; ks++) {
      bf16x8 af[4], bfr[CT];
#pragma unroll
      for (int rt = 0; rt < 4; rt++)
        af[rt] = *(const bf16x8*)&As[wm + rt * 16 + l15][ks * 32 + quad * 8];
#pragma unroll
      for (int ct = 0; ct < CT; ct++)
        bfr[ct] = *(const bf16x8*)&Bs[wn + ct * 16 + l15][ks * 32 + quad * 8];
#pragma unroll
      for (int rt = 0; rt < 4; rt++)
#pragma unroll
        for (int ct = 0; ct < CT; ct++)
          acc[rt][ct] = __builtin_amdgcn_mfma_f32_16x16x32_bf16(bfr[ct], af[rt], acc[rt][ct], 0, 0, 0);
    }
    __syncthreads();
  }

#pragma unroll
  for (int rt = 0; rt < 4; rt++) {
#pragma unroll
    for (int ct = 0; ct < CT; ct++) {
      int m = m0 + wm + rt * 16 + l15;
      int nb = n0 + wn + ct * 16 + quad * 4;
      float4 b4 = *(const float4*)&bias[nb];
      float v0 = acc[rt][ct][0] + b4.x, v1 = acc[rt][ct][1] + b4.y;
      float v2 = acc[rt][ct][2] + b4.z, v3 = acc[rt][ct][3] + b4.w;
      if (MODE == 0) {
        int sel = nb >> 10;
        int c = nb & 1023;
        int h = c >> 6, d0 = c & 63;
        int b = m >> 11, t = m & 2047;
        u16* dst = (sel == 0) ? qb : (sel == 1) ? kb : vb;
        union { u32 u[2]; uint2 u2; } o;
        o.u[0] = pack_rn(v0, v1);
        o.u[1] = pack_rn(v2, v3);
        *(uint2*)&dst[((((size_t)b * NH + h) * TSEQ + t) << 6) + d0] = o.u2;
      } else {
        float4 o = {v0, v1, v2, v3};
        *(float4*)&outp[(size_t)m * N + nb] = o;
      }
    }
  }
}

// ---------------- flash attention: 32x32x16 MFMA, 2 waves x 32 q ----------------
// grid 1024 blocks x 128 threads; qt swizzled so each CU's 4 blocks have qt
// summing to 62 (R5-proven balance). 32x32x16 has 2x arithmetic intensity per
// input byte vs 16x16x32 -> halves the K/V LDS fragment traffic per q-row.
// C/D layout (m74/m101-verified): col=lane&31, row=(reg&3)+8*(reg>>2)+4*(lane>>5).
// A: row=lane&31, k=(lane>>5)*8+j.  B: col=lane&31, k=(lane>>5)*8+j.
// Fixed-M softmax (exact, shift-invariant). P via wave-private [32][36] slab.

__global__ __launch_bounds__(128) void attn_kernel(const u16* __restrict__ Qb,
                                                   const u16* __restrict__ Kb,
                                                   const u16* __restrict__ Vtb,
                                                   u16* __restrict__ O) {
  __shared__ u16 Ks[64][68];
  __shared__ u16 Vt[64][68];
  __shared__ u16 Ps[2][32][36];

  const float SCL = 0.18033688f;   // (1/8) * log2(e)
  const float MOFF = 16.0f;

  int id = blockIdx.x;
  int bh = (id >> 5) & 31;
  int q5 = id & 31;
  int qt = ((id >> 8) & 1) ? (31 - q5) : q5;

  int tid = threadIdx.x, lane = tid & 63, w = tid >> 6;   // w in {0,1}
  int l31 = lane & 31, h = lane >> 5;
  const size_t hoff = (size_t)bh * TSEQ * 64;

  int qw = qt * 64 + w * 32;        // wave's q base
  int qg = qw + l31;                // lane's q column

  // Q B-operand fragments: qf[s] = Q[qg][s*16 + h*8 .. +7]
  bf16x8 qf[4];
  {
    const u16* qp = Qb + hoff + (size_t)qg * 64 + h * 8;
#pragma unroll
    for (int s = 0; s < 4; s++) qf[s] = *(const bf16x8*)(qp + s * 16);
  }

  f32x16 acc[2];
  acc[0] = zero16(); acc[1] = zero16();
  float l_i = 0.f;

  // staging: thread covers row r, 32 cols at cb
  int r = tid >> 1, cb = (tid & 1) * 32;
  bf16x8 kr[4], vr[4];
  {
    const u16* kg = Kb + hoff + (size_t)r * 64 + cb;
    const u16* vg = Vtb + hoff + (size_t)r * TSEQ + cb;
#pragma unroll
    for (int c = 0; c < 4; c++) {
      kr[c] = *(const bf16x8*)(kg + c * 8);
      vr[c] = *(const bf16x8*)(vg + c * 8);
    }
  }

  for (int kt = 0; kt <= qt; kt++) {
    __syncthreads();                       // prev iter's readers done
#pragma unroll
    for (int c = 0; c < 4; c++) {
      *(bf16x8*)&Ks[r][cb + c * 8] = kr[c];
      *(bf16x8*)&Vt[r][cb + c * 8] = vr[c];
    }
    __syncthreads();                       // tile visible
    if (kt < qt) {                         // prefetch next tile; overlaps compute
      const u16* kg = Kb + hoff + (size_t)((kt + 1) * 64 + r) * 64 + cb;
      const u16* vg = Vtb + hoff + (size_t)r * TSEQ + (kt + 1) * 64 + cb;
#pragma unroll
      for (int c = 0; c < 4; c++) {
        kr[c] = *(const bf16x8*)(kg + c * 8);
        vr[c] = *(const bf16x8*)(vg + c * 8);
      }
    }

    int kb64 = kt * 64;
#pragma unroll
    for (int t = 0; t < 2; t++) {
      int kbt = kb64 + t * 32;
      if (kbt > qw + 31) continue;         // fully-masked tile (wave-uniform)

      // S^T tile = K Q^T : col = q, row = key_local
      f32x16 sacc = zero16();
#pragma unroll
      for (int s = 0; s < 4; s++) {
        bf16x8 kf = *(const bf16x8*)&Ks[t * 32 + l31][s * 16 + h * 8];
        sacc = __builtin_amdgcn_mfma_f32_32x32x16_bf16(kf, qf[s], sacc, 0, 0, 0);
      }

      if (kbt + 31 > qw) {                 // diagonal band: apply causal mask
#pragma unroll
        for (int rr = 0; rr < 16; rr++) {
          int key = kbt + (rr & 3) + 8 * (rr >> 2) + 4 * h;
          if (key > qg) sacc[rr] = -1e30f;
        }
      }

#pragma unroll
      for (int rr = 0; rr < 16; rr++) {
        float p = exp2f(__builtin_fmaf(sacc[rr], SCL, -MOFF));
        sacc[rr] = p;
        l_i += p;
      }

      // P^T (C-layout) -> [q][key] slab; b64 writes, 2-way banks, 8B-aligned
#pragma unroll
      for (int G = 0; G < 4; G++) {
        union { u32 u[2]; uint2 u2; } o;
        o.u[0] = pack_rn(sacc[4 * G + 0], sacc[4 * G + 1]);
        o.u[1] = pack_rn(sacc[4 * G + 2], sacc[4 * G + 3]);
        *(uint2*)&Ps[w][l31][G * 8 + 4 * h] = o.u2;
      }

      // O^T += V^T P over this 32-key tile
#pragma unroll
      for (int s2 = 0; s2 < 2; s2++) {
        union { bf16x8 v; uint2 d[2]; } pu;
        pu.d[0] = *(const uint2*)&Ps[w][l31][s2 * 16 + h * 8];
        pu.d[1] = *(const uint2*)&Ps[w][l31][s2 * 16 + h * 8 + 4];
#pragma unroll
        for (int dt = 0; dt < 2; dt++) {
          bf16x8 vf = *(const bf16x8*)&Vt[dt * 32 + l31][t * 32 + s2 * 16 + h * 8];
          acc[dt] = __builtin_amdgcn_mfma_f32_32x32x16_bf16(vf, pu.v, acc[dt], 0, 0, 0);
        }
      }
    }
  }

  l_i += __shfl_xor(l_i, 32);
  float inv = 1.0f / l_i;

  int b = bh >> 4, head = bh & 15;
  size_t rowbase = ((size_t)b * TSEQ + qg) * 1024 + head * 64;
#pragma unroll
  for (int dt = 0; dt < 2; dt++)
#pragma unroll
    for (int G = 0; G < 4; G++) {
      union { u32 u[2]; uint2 u2; } o;
      o.u[0] = pack_rn(acc[dt][4 * G + 0] * inv, acc[dt][4 * G + 1] * inv);
      o.u[1] = pack_rn(acc[dt][4 * G + 2] * inv, acc[dt][4 * G + 3] * inv);
      *(uint2*)&O[rowbase + dt * 32 + G * 8 + 4 * h] = o.u2;
    }
}

// ---------------- launch ----------------

extern "C" void kernel_launch(void* const* d_in, const int* in_sizes, int n_in,
                              void* d_out, int out_size, void* d_ws, size_t ws_size,
                              hipStream_t stream) {
  (void)in_sizes; (void)n_in; (void)out_size; (void)ws_size;
  const float* x     = (const float*)d_in[0];
  const float* w_qkv = (const float*)d_in[1];
  const float* b_qkv = (const float*)d_in[2];
  const float* w_out = (const float*)d_in[3];
  const float* b_out = (const float*)d_in[4];
  float* out = (float*)d_out;

  char* p = (char*)d_ws;
  u16* x_bf  = (u16*)p; p += (size_t)TOK * EMB * 2;       // 8 MiB (dead after gemm0)
  u16* wqkvT = (u16*)p; p += (size_t)NQKV * EMB * 2;      // 6 MiB
  u16* woutT = (u16*)p; p += (size_t)EMB * EMB * 2;       // 2 MiB
  u16* Qb    = (u16*)p; p += (size_t)32 * TSEQ * 64 * 2;  // 8 MiB  [bh][t][d]
  u16* Kb    = (u16*)p; p += (size_t)32 * TSEQ * 64 * 2;  //        [bh][t][d]
  u16* Vraw  = (u16*)p; p += (size_t)32 * TSEQ * 64 * 2;  //        [bh][t][d]
  u16* attn_o = (u16*)p;                                  // 8 MiB
  u16* Vtb   = x_bf;   // alias: x_bf dead once gemm0 completes (stream-ordered)

  prep_kernel<<<dim3(4096 + 768 + 256), 256, 0, stream>>>(x, x_bf, w_qkv, wqkvT, w_out, woutT);
  gemm_bt<0, 128><<<dim3(NQKV / 128, TOK / 128), 256, 0, stream>>>(x_bf, wqkvT, b_qkv,
                                                                   Qb, Kb, Vraw, nullptr, EMB, NQKV);
  transpose_v<<<dim3(TSEQ / 64, 32), 256, 0, stream>>>(Vraw, Vtb);
  attn_kernel<<<dim3(1024), 128, 0, stream>>>(Qb, Kb, Vtb, attn_o);
  gemm_bt<1, 64><<<dim3(EMB / 128, TOK / 64), 256, 0, stream>>>(attn_o, woutT, b_out,
                                                                nullptr, nullptr, nullptr, out, EMB, EMB);
}

// Round 9
// 186.509 us; speedup vs baseline: 1.1359x; 1.1359x over previous
//
#include <hip/hip_runtime.h>

typedef unsigned short u16;
typedef unsigned int u32;
typedef __attribute__((ext_vector_type(8))) short bf16x8;
typedef __attribute__((ext_vector_type(4))) float f32x4;
typedef __attribute__((ext_vector_type(16))) float f32x16;

#define TOK   4096   // B*T
#define EMB   1024
#define NQKV  3072
#define TSEQ  2048
#define NH    16

__device__ __forceinline__ u16 f2b(float f) {
  union { float f; unsigned u; } v; v.f = f;
  unsigned r = v.u + 0x7FFFu + ((v.u >> 16) & 1u);
  return (u16)(r >> 16);
}

// pack bf16(a) low16, bf16(b) high16 (round half-up)
__device__ __forceinline__ u32 pack_rn(float a, float b) {
  u32 ua = __float_as_uint(a) + 0x8000u;
  u32 ub = __float_as_uint(b) + 0x8000u;
  return __builtin_amdgcn_perm(ub, ua, 0x07060302u);
}

__device__ __forceinline__ f32x16 zero16() {
  f32x16 z;
#pragma unroll
  for (int i = 0; i < 16; i++) z[i] = 0.f;
  return z;
}

// ---------------- fused prep: x->bf16, w_qkv^T, w_out^T ----------------

__global__ __launch_bounds__(256) void prep_kernel(const float* __restrict__ x,
                                                   u16* __restrict__ x_bf,
                                                   const float* __restrict__ w_qkv,
                                                   u16* __restrict__ wqkvT,
                                                   const float* __restrict__ w_out,
                                                   u16* __restrict__ woutT) {
  __shared__ u16 sm[64][65];
  int bid = blockIdx.x, tid = threadIdx.x;
  if (bid < 4096) {                       // cvt: 1M float4 elements
    int i = bid * 256 + tid;
    float4 v = ((const float4*)x)[i];
    union { u16 us[4]; uint2 u2; } o;
    o.us[0] = f2b(v.x); o.us[1] = f2b(v.y); o.us[2] = f2b(v.z); o.us[3] = f2b(v.w);
    ((uint2*)x_bf)[i] = o.u2;
    return;
  }
  const float* src; u16* dst; int R, C, bx, by;
  if (bid < 4096 + 768) {                 // w_qkv: [1024][3072] -> [3072][1024]
    int t = bid - 4096; bx = t % 48; by = t / 48;
    src = w_qkv; dst = wqkvT; R = EMB; C = NQKV;
  } else {                                // w_out: [1024][1024] -> [1024][1024]
    int t = bid - 4096 - 768; bx = t & 15; by = t >> 4;
    src = w_out; dst = woutT; R = EMB; C = EMB;
  }
  int c0 = bx * 64, r0 = by * 64;
#pragma unroll
  for (int i = 0; i < 16; i++) {
    int idx = tid + i * 256;
    int r = idx >> 6, c = idx & 63;
    sm[r][c] = f2b(src[(size_t)(r0 + r) * C + c0 + c]);
  }
  __syncthreads();
#pragma unroll
  for (int i = 0; i < 16; i++) {
    int idx = tid + i * 256;
    int cc = idx >> 6, rr = idx & 63;
    dst[(size_t)(c0 + cc) * R + r0 + rr] = sm[rr][cc];
  }
}

// per-head transpose: V[bh][t][d] -> Vt[bh][d][t]
__global__ __launch_bounds__(256) void transpose_v(const u16* __restrict__ V,
                                                   u16* __restrict__ Vt) {
  __shared__ u16 sm[64][72];
  int t0 = blockIdx.x * 64, bh = blockIdx.y;
  size_t base = (size_t)bh * TSEQ * 64;
  int tid = threadIdx.x;
  int r = tid >> 2, c = (tid & 3) * 16;
  *(bf16x8*)&sm[r][c]     = *(const bf16x8*)&V[base + (size_t)(t0 + r) * 64 + c];
  *(bf16x8*)&sm[r][c + 8] = *(const bf16x8*)&V[base + (size_t)(t0 + r) * 64 + c + 8];
  __syncthreads();
  int d = tid >> 2, tc = (tid & 3) * 16;
  union { u16 us[16]; uint4 v4[2]; } o;
#pragma unroll
  for (int i = 0; i < 16; i++) o.us[i] = sm[tc + i][d];
  *(uint4*)&Vt[base + (size_t)d * TSEQ + t0 + tc]     = o.v4[0];
  *(uint4*)&Vt[base + (size_t)d * TSEQ + t0 + tc + 8] = o.v4[1];
}

// ---------------- GEMM: C[m][n] = sum_k A[m][k]*Bt[n][k] + bias[n] ----------------
// Stride-68 LDS (<=2-way bank aliasing, free) + register-staged tiles with
// cross-iteration prefetch. C^T orientation -> vectorized epilogue.
// MODE 0: uint2 bf16 scatter into Q/K/V [bh][t][d].  MODE 1: float4 fp32 [M][N].

template <int MODE, int TM>
__global__ __launch_bounds__(256) void gemm_bt(const u16* __restrict__ A,
                                               const u16* __restrict__ Bt,
                                               const float* __restrict__ bias,
                                               u16* __restrict__ qb, u16* __restrict__ kb,
                                               u16* __restrict__ vb, float* __restrict__ outp,
                                               int K, int N) {
  constexpr int LDA = 68;
  constexpr int CT = (TM == 128) ? 4 : 2;
  constexpr int AC = TM / 32;
  __shared__ u16 As[TM][LDA];
  __shared__ u16 Bs[128][LDA];
  int tid = threadIdx.x;
  int m0 = blockIdx.y * TM, n0 = blockIdx.x * 128;
  int lane = tid & 63, wid = tid >> 6;
  int wm = (TM == 128) ? (wid >> 1) * 64 : 0;
  int wn = (TM == 128) ? (wid & 1) * 64 : wid * 32;
  int l15 = lane & 15, quad = lane >> 4;
  int lrow = lane >> 3, lcol = (lane & 7) * 8;

  f32x4 acc[4][CT];
#pragma unroll
  for (int i = 0; i < 4; i++)
#pragma unroll
    for (int j = 0; j < CT; j++) acc[i][j] = (f32x4){0.f, 0.f, 0.f, 0.f};

  bf16x8 ar[AC], br[4];
#pragma unroll
  for (int i = 0; i < AC; i++)
    ar[i] = *(const bf16x8*)&A[(size_t)(m0 + (wid * AC + i) * 8 + lrow) * K + lcol];
#pragma unroll
  for (int i = 0; i < 4; i++)
    br[i] = *(const bf16x8*)&Bt[(size_t)(n0 + (wid * 4 + i) * 8 + lrow) * K + lcol];

  for (int k0 = 0; k0 < K; k0 += 64) {
#pragma unroll
    for (int i = 0; i < AC; i++)
      *(bf16x8*)&As[(wid * AC + i) * 8 + lrow][lcol] = ar[i];
#pragma unroll
    for (int i = 0; i < 4; i++)
      *(bf16x8*)&Bs[(wid * 4 + i) * 8 + lrow][lcol] = br[i];
    __syncthreads();

    if (k0 + 64 < K) {
      int kn = k0 + 64;
#pragma unroll
      for (int i = 0; i < AC; i++)
        ar[i] = *(const bf16x8*)&A[(size_t)(m0 + (wid * AC + i) * 8 + lrow) * K + kn + lcol];
#pragma unroll
      for (int i = 0; i < 4; i++)
        br[i] = *(const bf16x8*)&Bt[(size_t)(n0 + (wid * 4 + i) * 8 + lrow) * K + kn + lcol];
    }

#pragma unroll
    for (int ks = 0; ks < 2; ks++) {
      bf16x8 af[4], bfr[CT];
#pragma unroll
      for (int rt = 0; rt < 4; rt++)
        af[rt] = *(const bf16x8*)&As[wm + rt * 16 + l15][ks * 32 + quad * 8];
#pragma unroll
      for (int ct = 0; ct < CT; ct++)
        bfr[ct] = *(const bf16x8*)&Bs[wn + ct * 16 + l15][ks * 32 + quad * 8];
#pragma unroll
      for (int rt = 0; rt < 4; rt++)
#pragma unroll
        for (int ct = 0; ct < CT; ct++)
          acc[rt][ct] = __builtin_amdgcn_mfma_f32_16x16x32_bf16(bfr[ct], af[rt], acc[rt][ct], 0, 0, 0);
    }
    __syncthreads();
  }

#pragma unroll
  for (int rt = 0; rt < 4; rt++) {
#pragma unroll
    for (int ct = 0; ct < CT; ct++) {
      int m = m0 + wm + rt * 16 + l15;
      int nb = n0 + wn + ct * 16 + quad * 4;
      float4 b4 = *(const float4*)&bias[nb];
      float v0 = acc[rt][ct][0] + b4.x, v1 = acc[rt][ct][1] + b4.y;
      float v2 = acc[rt][ct][2] + b4.z, v3 = acc[rt][ct][3] + b4.w;
      if (MODE == 0) {
        int sel = nb >> 10;
        int c = nb & 1023;
        int h = c >> 6, d0 = c & 63;
        int b = m >> 11, t = m & 2047;
        u16* dst = (sel == 0) ? qb : (sel == 1) ? kb : vb;
        union { u32 u[2]; uint2 u2; } o;
        o.u[0] = pack_rn(v0, v1);
        o.u[1] = pack_rn(v2, v3);
        *(uint2*)&dst[((((size_t)b * NH + h) * TSEQ + t) << 6) + d0] = o.u2;
      } else {
        float4 o = {v0, v1, v2, v3};
        *(float4*)&outp[(size_t)m * N + nb] = o;
      }
    }
  }
}

// ---------------- flash attention: 32x32 MFMA, 4 waves = 2 q-subtiles x 2 key-halves --
// grid 1024 x 256 threads; qt swizzled so each CU's 4 blocks have qt summing to 62
// (R5-proven balance) -> 16 waves/CU. Fixed-M softmax is ASSOCIATIVE (no running
// max), so the key dimension splits freely across waves: wave (sub,par) handles
// q rows [qt*64+sub*32, +32) x keys [kt*64+par*32, +32) per staged tile; partial
// (O, l) summed across par at the end via LDS. P transform C-layout->B-layout is
// pure in-register: B-frag dwords = reg-pairs 8s2+4h+{0..3} of the same l31 lane,
// half-swapped -> 2x shfl_xor(32) + cndmask per 16-key chunk. No LDS for P.

__global__ __launch_bounds__(256, 4) void attn_kernel(const u16* __restrict__ Qb,
                                                      const u16* __restrict__ Kb,
                                                      const u16* __restrict__ Vtb,
                                                      u16* __restrict__ O) {
  __shared__ u16 Ks[64][68];
  __shared__ u16 Vt[64][68];
  __shared__ float Cmb[2][16][64][2];   // [sub][pair][lane][2] — 2-way banks, b64 ops
  __shared__ float Lmb[2][32];

  const float SCL = 0.18033688f;   // (1/8) * log2(e)
  const float MOFF = 16.0f;

  int id = blockIdx.x;
  int bh = (id >> 5) & 31;
  int q5 = id & 31;
  int qt = ((id >> 8) & 1) ? (31 - q5) : q5;

  int tid = threadIdx.x, lane = tid & 63, w = tid >> 6;
  int sub = w & 1, par = w >> 1;
  int l31 = lane & 31, h = lane >> 5;
  const size_t hoff = (size_t)bh * TSEQ * 64;

  int qw = qt * 64 + sub * 32;      // wave's q base
  int qg = qw + l31;                // lane's q column

  // Q B-operand fragments: qf[s] = Q[qg][s*16 + h*8 .. +7]
  bf16x8 qf[4];
  {
    const u16* qp = Qb + hoff + (size_t)qg * 64 + h * 8;
#pragma unroll
    for (int s = 0; s < 4; s++) qf[s] = *(const bf16x8*)(qp + s * 16);
  }

  f32x16 acc[2];
  acc[0] = zero16(); acc[1] = zero16();
  float l_i = 0.f;

  // staging: thread covers K row r cols [cb,cb+16) and V^T row r cols [cb,cb+16)
  int r = tid >> 2, cb = (tid & 3) * 16;
  bf16x8 kr0, kr1, vr0, vr1;
  {
    const u16* kg = Kb + hoff + (size_t)r * 64 + cb;
    const u16* vg = Vtb + hoff + (size_t)r * TSEQ + cb;
    kr0 = *(const bf16x8*)kg;       kr1 = *(const bf16x8*)(kg + 8);
    vr0 = *(const bf16x8*)vg;       vr1 = *(const bf16x8*)(vg + 8);
  }

  for (int kt = 0; kt <= qt; kt++) {
    __syncthreads();                       // prev iter's readers done
    *(bf16x8*)&Ks[r][cb]     = kr0;
    *(bf16x8*)&Ks[r][cb + 8] = kr1;
    *(bf16x8*)&Vt[r][cb]     = vr0;
    *(bf16x8*)&Vt[r][cb + 8] = vr1;
    __syncthreads();                       // tile visible
    if (kt < qt) {                         // prefetch next tile; overlaps compute
      const u16* kg = Kb + hoff + (size_t)((kt + 1) * 64 + r) * 64 + cb;
      const u16* vg = Vtb + hoff + (size_t)r * TSEQ + (kt + 1) * 64 + cb;
      kr0 = *(const bf16x8*)kg;     kr1 = *(const bf16x8*)(kg + 8);
      vr0 = *(const bf16x8*)vg;     vr1 = *(const bf16x8*)(vg + 8);
    }

    int kbt = kt * 64 + par * 32;          // wave's 32-key chunk base
    if (kbt <= qw + 31) {                  // skip fully-masked quadrant (wave-uniform)
      // S^T quadrant = K Q^T : col = q (l31), rows = 32 keys of this chunk
      f32x16 sacc = zero16();
#pragma unroll
      for (int s = 0; s < 4; s++) {
        bf16x8 kf = *(const bf16x8*)&Ks[par * 32 + l31][s * 16 + h * 8];
        sacc = __builtin_amdgcn_mfma_f32_32x32x16_bf16(kf, qf[s], sacc, 0, 0, 0);
      }

      if (kbt + 31 > qw) {                 // diagonal band: apply causal mask
#pragma unroll
        for (int rr = 0; rr < 16; rr++) {
          int key = kbt + (rr & 3) + 8 * (rr >> 2) + 4 * h;
          if (key > qg) sacc[rr] = -1e30f;
        }
      }

#pragma unroll
      for (int rr = 0; rr < 16; rr++) {
        float p = exp2f(__builtin_fmaf(sacc[rr], SCL, -MOFF));
        sacc[rr] = p;
        l_i += p;
      }

      // per 16-key chunk: in-register C->B transform, then PV
#pragma unroll
      for (int s2 = 0; s2 < 2; s2++) {
        u32 u0 = pack_rn(sacc[8 * s2 + 0], sacc[8 * s2 + 1]);
        u32 u1 = pack_rn(sacc[8 * s2 + 2], sacc[8 * s2 + 3]);
        u32 u2 = pack_rn(sacc[8 * s2 + 4], sacc[8 * s2 + 5]);
        u32 u3 = pack_rn(sacc[8 * s2 + 6], sacc[8 * s2 + 7]);
        u32 s0 = h ? u0 : u2, s1 = h ? u1 : u3;     // what the other half needs from me
        u32 t0 = (u32)__shfl_xor((int)s0, 32);
        u32 t1 = (u32)__shfl_xor((int)s1, 32);
        union { u32 d[4]; bf16x8 v; } pf;
        pf.d[0] = h ? t0 : u0;
        pf.d[1] = h ? t1 : u1;
        pf.d[2] = h ? u2 : t0;
        pf.d[3] = h ? u3 : t1;
#pragma unroll
        for (int dt = 0; dt < 2; dt++) {
          bf16x8 vf = *(const bf16x8*)&Vt[dt * 32 + l31][par * 32 + s2 * 16 + h * 8];
          acc[dt] = __builtin_amdgcn_mfma_f32_32x32x16_bf16(vf, pf.v, acc[dt], 0, 0, 0);
        }
      }
    }
  }

  l_i += __shfl_xor(l_i, 32);              // combine h halves within wave

  __syncthreads();                          // loop LDS traffic done
  if (par == 1) {                           // export partials
#pragma unroll
    for (int dt = 0; dt < 2; dt++)
#pragma unroll
      for (int pr = 0; pr < 8; pr++) {
        Cmb[sub][dt * 8 + pr][lane][0] = acc[dt][2 * pr];
        Cmb[sub][dt * 8 + pr][lane][1] = acc[dt][2 * pr + 1];
      }
    if (h == 0) Lmb[sub][l31] = l_i;
  }
  __syncthreads();
  if (par == 0) {                           // combine + write O
#pragma unroll
    for (int dt = 0; dt < 2; dt++)
#pragma unroll
      for (int pr = 0; pr < 8; pr++) {
        acc[dt][2 * pr]     += Cmb[sub][dt * 8 + pr][lane][0];
        acc[dt][2 * pr + 1] += Cmb[sub][dt * 8 + pr][lane][1];
      }
    float lt = l_i + Lmb[sub][l31];
    float inv = 1.0f / lt;

    int b = bh >> 4, head = bh & 15;
    size_t rowbase = ((size_t)b * TSEQ + qg) * 1024 + head * 64;
#pragma unroll
    for (int dt = 0; dt < 2; dt++)
#pragma unroll
      for (int G = 0; G < 4; G++) {
        union { u32 u[2]; uint2 u2; } o;
        o.u[0] = pack_rn(acc[dt][4 * G + 0] * inv, acc[dt][4 * G + 1] * inv);
        o.u[1] = pack_rn(acc[dt][4 * G + 2] * inv, acc[dt][4 * G + 3] * inv);
        *(uint2*)&O[rowbase + dt * 32 + G * 8 + 4 * h] = o.u2;
      }
  }
}

// ---------------- launch ----------------

extern "C" void kernel_launch(void* const* d_in, const int* in_sizes, int n_in,
                              void* d_out, int out_size, void* d_ws, size_t ws_size,
                              hipStream_t stream) {
  (void)in_sizes; (void)n_in; (void)out_size; (void)ws_size;
  const float* x     = (const float*)d_in[0];
  const float* w_qkv = (const float*)d_in[1];
  const float* b_qkv = (const float*)d_in[2];
  const float* w_out = (const float*)d_in[3];
  const float* b_out = (const float*)d_in[4];
  float* out = (float*)d_out;

  char* p = (char*)d_ws;
  u16* x_bf  = (u16*)p; p += (size_t)TOK * EMB * 2;       // 8 MiB (dead after gemm0)
  u16* wqkvT = (u16*)p; p += (size_t)NQKV * EMB * 2;      // 6 MiB
  u16* woutT = (u16*)p; p += (size_t)EMB * EMB * 2;       // 2 MiB
  u16* Qb    = (u16*)p; p += (size_t)32 * TSEQ * 64 * 2;  // 8 MiB  [bh][t][d]
  u16* Kb    = (u16*)p; p += (size_t)32 * TSEQ * 64 * 2;  //        [bh][t][d]
  u16* Vraw  = (u16*)p; p += (size_t)32 * TSEQ * 64 * 2;  //        [bh][t][d]
  u16* attn_o = (u16*)p;                                  // 8 MiB
  u16* Vtb   = x_bf;   // alias: x_bf dead once gemm0 completes (stream-ordered)

  prep_kernel<<<dim3(4096 + 768 + 256), 256, 0, stream>>>(x, x_bf, w_qkv, wqkvT, w_out, woutT);
  gemm_bt<0, 128><<<dim3(NQKV / 128, TOK / 128), 256, 0, stream>>>(x_bf, wqkvT, b_qkv,
                                                                   Qb, Kb, Vraw, nullptr, EMB, NQKV);
  transpose_v<<<dim3(TSEQ / 64, 32), 256, 0, stream>>>(Vraw, Vtb);
  attn_kernel<<<dim3(1024), 256, 0, stream>>>(Qb, Kb, Vtb, attn_o);
  gemm_bt<1, 64><<<dim3(EMB / 128, TOK / 64), 256, 0, stream>>>(attn_o, woutT, b_out,
                                                                nullptr, nullptr, nullptr, out, EMB, EMB);
}